// Round 4
// baseline (208.919 us; speedup 1.0000x reference)
//
#include <hip/hip_runtime.h>
#include <hip/hip_bf16.h>
#include <hip/hip_cooperative_groups.h>
#include <math.h>

namespace cg = cooperative_groups;

#define Bsz 8
#define Hh 64
#define Ww 64
#define Cc 256
#define Nn 64
#define Ll 4096      /* Hh*Ww */
#define EPSf 1e-5f

typedef __bf16 v8bf __attribute__((ext_vector_type(8)));
typedef float  f32x4 __attribute__((ext_vector_type(4)));

__device__ __forceinline__ float ad_val(float a, float snr) {
    float s = fminf(fmaxf(snr, 0.f), 1.f);
    float scale = 0.6f + 0.4f * s;
    float v = tanhf(a) * scale;
    return fminf(fmaxf(v, -0.99f), 0.99f);
}

__device__ __forceinline__ v8bf cvt8(float4 a, float4 b) {
    v8bf r;
    r[0] = (__bf16)a.x; r[1] = (__bf16)a.y; r[2] = (__bf16)a.z; r[3] = (__bf16)a.w;
    r[4] = (__bf16)b.x; r[5] = (__bf16)b.y; r[6] = (__bf16)b.z; r[7] = (__bf16)b.w;
    return r;
}

// K0: weights -> bf16 MFMA B-fragment order; WB = rowsum(Win)*Bp.
// grid 9: blocks 0-3 Win (hi/lo split), 4-7 Wout, 8 WB.
__global__ __launch_bounds__(256) void k0_weights(
    const float* __restrict__ Win, const float* __restrict__ Wout,
    const float* __restrict__ Bp, __bf16* __restrict__ Wh,
    __bf16* __restrict__ Wl, __bf16* __restrict__ Wo, float* __restrict__ WB)
{
    const int t = threadIdx.x;
    const int blk = blockIdx.x;
    if (blk < 4) {
        for (int idx = blk * 512 + t; idx < blk * 512 + 512; idx += 256) {
            int tile = idx >> 6, lane = idx & 63;
            int kt = tile >> 2, nt = tile & 3;
            int q = lane >> 4, n = nt * 16 + (lane & 15);
            #pragma unroll
            for (int j = 0; j < 8; ++j) {
                int k = kt * 32 + q * 8 + j;
                float w = Win[n * Cc + k];
                __bf16 h = (__bf16)w;
                Wh[idx * 8 + j] = h;
                Wl[idx * 8 + j] = (__bf16)(w - (float)h);
            }
        }
    } else if (blk < 8) {
        for (int idx = (blk - 4) * 512 + t; idx < (blk - 4) * 512 + 512; idx += 256) {
            int tile = idx >> 6, lane = idx & 63;
            int kt = tile >> 4, ntg = tile & 15;
            int q = lane >> 4, c = ntg * 16 + (lane & 15);
            #pragma unroll
            for (int j = 0; j < 8; ++j)
                Wo[idx * 8 + j] = (__bf16)Wout[c * Nn + kt * 32 + q * 8 + j];
        }
    } else {
        __shared__ float wtmp[256];
        int n = t >> 2, qd = t & 3;
        float s = 0.f;
        const float* wr = Win + (long)n * Cc + qd * 64;
        for (int i = 0; i < 64; ++i) s += wr[i];
        wtmp[t] = s;
        __syncthreads();
        if (t < 64)
            WB[t] = (wtmp[t*4] + wtmp[t*4+1] + wtmp[t*4+2] + wtmp[t*4+3]) * Bp[t];
    }
}

// K1: LN stats + MFMA input projection on raw x (LN folded into epilogue):
//   Bu[p][n] = Bp[n]*s[p]*((x@Win^T)[p][n]) - s[p]*m[p]*WB[n].
// x staged in LDS ONCE (stats computed during staging); Bu written coalesced.
__global__ __launch_bounds__(256) void k1_ln_gemm(
    const float* __restrict__ x, const __bf16* __restrict__ Wh,
    const __bf16* __restrict__ Wl, const float* __restrict__ Bp,
    const float* __restrict__ WB, float* __restrict__ Bu,
    float* __restrict__ Mst, float* __restrict__ Sst)
{
    __shared__ float xs[64 * 260];          // x tile; aliased for Bu staging later
    __shared__ float mrow[64], srow[64];
    const int t = threadIdx.x;
    const int lane = t & 63;
    const int wv = __builtin_amdgcn_readfirstlane(t >> 6);
    const long pbase = (long)blockIdx.x * 64;
    const float4* xg = (const float4*)(x + pbase * Cc);

    // staged load + per-row stats. fi = i*256+t -> row r = i*4+wv, col4 = lane.
    for (int i = 0; i < 16; ++i) {
        int r = i * 4 + wv;
        float4 v = xg[i * 256 + t];
        *(float4*)&xs[r * 260 + lane * 4] = v;
        float s = v.x + v.y + v.z + v.w;
        float q = v.x*v.x + v.y*v.y + v.z*v.z + v.w*v.w;
        #pragma unroll
        for (int off = 32; off > 0; off >>= 1) {
            s += __shfl_down(s, off);
            q += __shfl_down(q, off);
        }
        if (lane == 0) {
            float m = s * (1.f/256.f);
            float var = fmaxf(q * (1.f/256.f) - m*m, 0.f);
            float r1 = rsqrtf(var + EPSf);
            float v2 = var / (var + EPSf);
            float sc = r1 * rsqrtf(v2 + EPSf);   // combined LN(LN(.)) scale
            mrow[r] = m; srow[r] = sc;
            Mst[pbase + r] = m; Sst[pbase + r] = sc;
        }
    }
    __syncthreads();

    const int q = lane >> 4;
    const int mi = lane & 15;

    f32x4 acc[4];
    #pragma unroll
    for (int nt = 0; nt < 4; ++nt) acc[nt] = (f32x4){0.f, 0.f, 0.f, 0.f};

    #pragma unroll
    for (int kt = 0; kt < 8; ++kt) {
        const float* ar = &xs[(wv * 16 + mi) * 260 + q * 8 + kt * 32];
        float4 a0 = *(const float4*)ar;
        float4 a1 = *(const float4*)(ar + 4);
        float av[8] = {a0.x, a0.y, a0.z, a0.w, a1.x, a1.y, a1.z, a1.w};
        v8bf ah, al;
        #pragma unroll
        for (int j = 0; j < 8; ++j) {
            __bf16 h = (__bf16)av[j];
            ah[j] = h;
            al[j] = (__bf16)(av[j] - (float)h);
        }
        #pragma unroll
        for (int nt = 0; nt < 4; ++nt) {
            v8bf bh = *(const v8bf*)(Wh + ((long)(kt * 4 + nt) * 64 + lane) * 8);
            v8bf bl = *(const v8bf*)(Wl + ((long)(kt * 4 + nt) * 64 + lane) * 8);
            acc[nt] = __builtin_amdgcn_mfma_f32_16x16x32_bf16(ah, bh, acc[nt], 0, 0, 0);
            acc[nt] = __builtin_amdgcn_mfma_f32_16x16x32_bf16(al, bh, acc[nt], 0, 0, 0);
            acc[nt] = __builtin_amdgcn_mfma_f32_16x16x32_bf16(ah, bl, acc[nt], 0, 0, 0);
        }
    }

    // epilogue values (C/D layout: pos = wv*16+q*4+reg, n = nt*16+mi)
    float mv[4], sv[4];
    #pragma unroll
    for (int reg = 0; reg < 4; ++reg) {
        int p = wv * 16 + q * 4 + reg;
        mv[reg] = mrow[p]; sv[reg] = srow[p];
    }
    float buv[4][4];
    #pragma unroll
    for (int nt = 0; nt < 4; ++nt) {
        int n = nt * 16 + mi;
        float bpn = Bp[n], wbn = WB[n];
        #pragma unroll
        for (int reg = 0; reg < 4; ++reg)
            buv[nt][reg] = sv[reg] * (acc[nt][reg] * bpn - mv[reg] * wbn);
    }
    __syncthreads();                    // xs now dead; alias as Bu staging
    #pragma unroll
    for (int nt = 0; nt < 4; ++nt) {
        int n = nt * 16 + mi;
        #pragma unroll
        for (int reg = 0; reg < 4; ++reg)
            xs[(wv * 16 + q * 4 + reg) * 68 + n] = buv[nt][reg];
    }
    __syncthreads();
    float4* bug = (float4*)(Bu + pbase * Nn);
    #pragma unroll
    for (int i = 0; i < 4; ++i) {
        int fi = i * 256 + t;           // p = fi>>4, n4 = fi&15
        bug[fi] = *(const float4*)&xs[(fi >> 4) * 68 + (fi & 15) * 4];
    }
}

// K2 (cooperative): full scan phase for all 4 directions.
// Phase 1: per-tile local fwd/bwd scans (kept in LDS), chunk carries -> E.
// grid.sync(). Phase 2: inline carry prefix from E (Ad^64 composition), then
// elementwise combine by linearity: h[k] = local[k] + Ad^{k+1}*carry.
// 1024 blocks x 64 thr; LDS 33.3 KiB -> exactly 4 co-resident blocks/CU.
__global__ __launch_bounds__(64) void k2_scan(
    const float* __restrict__ Bu, const float* __restrict__ A,
    const float* __restrict__ snr, const float* __restrict__ Cp,
    float* __restrict__ E, float* __restrict__ Srow, float* __restrict__ Scol)
{
    __shared__ float tile[64 * 65];     // holds Bu tile, then bwd locals
    __shared__ float hf[64 * 65];       // fwd locals
    const int lane = threadIdx.x;
    const int id = blockIdx.x;
    const int isCol = id >> 9;
    const int b = (id >> 6) & 7;
    const int j = id & 63;
    const float Ad = ad_val(A[lane], snr[b]);
    const float cp = 0.25f * Cp[lane];
    const float* src = Bu + ((long)b * Ll + (isCol ? j : j * 64)) * Nn;
    const long stride = isCol ? (long)Ww * Nn : Nn;
    for (int k = 0; k < 64; ++k)
        tile[k * 65 + lane] = src[k * stride + lane];   // same-lane use only

    float s = 0.f;
    #pragma unroll 8
    for (int k = 0; k < 64; ++k) {
        s = fmaf(Ad, s, tile[k * 65 + lane]);
        hf[k * 65 + lane] = s;
    }
    const int dF = isCol ? 2 : 0;
    E[((dF * 8 + b) * 64 + j) * 64 + lane] = s;
    float sb = 0.f;
    #pragma unroll 8
    for (int k = 63; k >= 0; --k) {
        sb = fmaf(Ad, sb, tile[k * 65 + lane]);
        tile[k * 65 + lane] = sb;       // overwrite after last use
    }
    E[(((dF + 1) * 8 + b) * 64 + (63 - j)) * 64 + lane] = sb;

    cg::this_grid().sync();

    float p64 = Ad;
    #pragma unroll
    for (int i = 0; i < 6; ++i) p64 *= p64;   // Ad^64
    float cf = 0.f;
    const float* Ef = E + (long)((dF * 8 + b) * 64) * 64;
    for (int i = 0; i < j; ++i) cf = fmaf(p64, cf, Ef[i * 64 + lane]);
    float cb = 0.f;
    const float* Eb = E + (long)(((dF + 1) * 8 + b) * 64) * 64;
    const int jj = 63 - j;
    for (int i = 0; i < jj; ++i) cb = fmaf(p64, cb, Eb[i * 64 + lane]);

    float* out0 = (isCol ? Scol : Srow) + ((long)b * Ll + (isCol ? j : j * 64)) * Nn;
    float pw = Ad;
    #pragma unroll 8
    for (int k = 0; k < 64; ++k) {
        hf[k * 65 + lane] = fmaf(pw, cf, hf[k * 65 + lane]);
        pw *= Ad;
    }
    float pwb = Ad;
    #pragma unroll 8
    for (int k = 63; k >= 0; --k) {
        float val = fmaf(pwb, cb, tile[k * 65 + lane]);
        out0[k * stride + lane] = cp * (hf[k * 65 + lane] + val);
        pwb *= Ad;
    }
}

// K5: MFMA output projection y = S @ Wout^T + D*z, S = Srow+Scol.
// 512 blocks x 256 thr; block = 64 pos x 256 ch. S staged in LDS; accumulator
// round-trips through LDS so x-read + out-write are pure float4 streams.
__global__ __launch_bounds__(256) void k5_gemm_out(
    const float* __restrict__ Srow, const float* __restrict__ Scol,
    const float* __restrict__ x, const __bf16* __restrict__ Wo,
    const float* __restrict__ Dp, const float* __restrict__ Mst,
    const float* __restrict__ Sst, float* __restrict__ out)
{
    __shared__ float smem[64 * 260];    // st (stride 68) -> ot (stride 260)
    const int t = threadIdx.x;
    const int lane = t & 63;
    const int wv = __builtin_amdgcn_readfirstlane(t >> 6);
    const long pbase = (long)blockIdx.x * 64;
    const int q = lane >> 4;
    const int mi = lane & 15;

    // stage S = Srow + Scol (coalesced float4)
    const float4* Sr = (const float4*)(Srow + pbase * Nn);
    const float4* Sc = (const float4*)(Scol + pbase * Nn);
    #pragma unroll
    for (int i = 0; i < 4; ++i) {
        int fi = i * 256 + t;           // p = fi>>4, n4 = fi&15
        float4 a = Sr[fi], c = Sc[fi];
        *(float4*)&smem[(fi >> 4) * 68 + (fi & 15) * 4] =
            make_float4(a.x + c.x, a.y + c.y, a.z + c.z, a.w + c.w);
    }
    __syncthreads();

    f32x4 acc[4][4];
    #pragma unroll
    for (int mt = 0; mt < 4; ++mt)
        #pragma unroll
        for (int nt = 0; nt < 4; ++nt) acc[mt][nt] = (f32x4){0.f, 0.f, 0.f, 0.f};

    #pragma unroll
    for (int kt = 0; kt < 2; ++kt) {
        v8bf bfr[4];
        #pragma unroll
        for (int nt = 0; nt < 4; ++nt)
            bfr[nt] = *(const v8bf*)(Wo + ((long)(kt * 16 + wv * 4 + nt) * 64 + lane) * 8);
        #pragma unroll
        for (int mt = 0; mt < 4; ++mt) {
            const float* ar = &smem[(mt * 16 + mi) * 68 + q * 8 + kt * 32];
            v8bf af = cvt8(*(const float4*)ar, *(const float4*)(ar + 4));
            #pragma unroll
            for (int nt = 0; nt < 4; ++nt)
                acc[mt][nt] = __builtin_amdgcn_mfma_f32_16x16x32_bf16(af, bfr[nt], acc[mt][nt], 0, 0, 0);
        }
    }
    __syncthreads();                    // st dead; reuse smem as out tile
    #pragma unroll
    for (int mt = 0; mt < 4; ++mt)
        #pragma unroll
        for (int nt = 0; nt < 4; ++nt) {
            int c = wv * 64 + nt * 16 + mi;
            #pragma unroll
            for (int reg = 0; reg < 4; ++reg)
                smem[(mt * 16 + q * 4 + reg) * 260 + c] = acc[mt][nt][reg];
        }
    __syncthreads();

    // epilogue: out = acc + D*z, fully coalesced float4 (p wave-uniform per i)
    const float4* xg = (const float4*)(x + pbase * Cc);
    float4* og = (float4*)(out + pbase * Cc);
    const float4 dv = ((const float4*)Dp)[lane];
    #pragma unroll 4
    for (int i = 0; i < 16; ++i) {
        int fi = i * 256 + t;           // p = i*4+wv (uniform), c4 = lane
        int p = i * 4 + wv;
        float4 v = *(const float4*)&smem[p * 260 + lane * 4];
        float m = Mst[pbase + p], s = Sst[pbase + p];
        float4 xv = xg[fi];
        og[fi] = make_float4(v.x + dv.x * ((xv.x - m) * s),
                             v.y + dv.y * ((xv.y - m) * s),
                             v.z + dv.z * ((xv.z - m) * s),
                             v.w + dv.w * ((xv.w - m) * s));
    }
}

extern "C" void kernel_launch(void* const* d_in, const int* in_sizes, int n_in,
                              void* d_out, int out_size, void* d_ws, size_t ws_size,
                              hipStream_t stream)
{
    const float* x    = (const float*)d_in[0];
    const float* snr  = (const float*)d_in[1];
    const float* A    = (const float*)d_in[2];
    const float* Bp   = (const float*)d_in[3];
    const float* Cp   = (const float*)d_in[4];
    const float* Dp   = (const float*)d_in[5];
    const float* Win  = (const float*)d_in[6];
    const float* Wout = (const float*)d_in[7];
    float* out = (float*)d_out;

    char* ws = (char*)d_ws;
    float*  Bu   = (float*)(ws);                                       // 8 MiB
    float*  Srow = (float*)(ws + (size_t)8  * 1024 * 1024);            // 8 MiB
    float*  Scol = (float*)(ws + (size_t)16 * 1024 * 1024);            // 8 MiB
    float*  E    = (float*)(ws + (size_t)24 * 1024 * 1024);            // 512 KiB
    float*  Mst  = (float*)(ws + (size_t)25 * 1024 * 1024);            // 128 KiB
    float*  Sst  = (float*)(ws + (size_t)25 * 1024 * 1024 + 128*1024); // 128 KiB
    char*   wbase = ws + (size_t)25 * 1024 * 1024 + 512 * 1024;
    __bf16* Wh   = (__bf16*)(wbase);                                   // 32 KiB
    __bf16* Wl   = (__bf16*)(wbase + 32 * 1024);                       // 32 KiB
    __bf16* Wo   = (__bf16*)(wbase + 64 * 1024);                       // 32 KiB
    float*  WB   = (float*)(wbase + 96 * 1024);                        // 256 B

    hipLaunchKernelGGL(k0_weights, dim3(9),   dim3(256), 0, stream, Win, Wout, Bp, Wh, Wl, Wo, WB);
    hipLaunchKernelGGL(k1_ln_gemm, dim3(512), dim3(256), 0, stream, x, Wh, Wl, Bp, WB, Bu, Mst, Sst);

    void* args[] = {(void*)&Bu, (void*)&A, (void*)&snr, (void*)&Cp,
                    (void*)&E, (void*)&Srow, (void*)&Scol};
    hipLaunchCooperativeKernel((void*)k2_scan, dim3(1024), dim3(64), args, 0, stream);

    hipLaunchKernelGGL(k5_gemm_out, dim3(512), dim3(256), 0, stream, Srow, Scol, x, Wo, Dp, Mst, Sst, out);
}

// Round 7
// 138.433 us; speedup vs baseline: 1.5092x; 1.5092x over previous
//
#include <hip/hip_runtime.h>
#include <hip/hip_bf16.h>
#include <math.h>

#define Bsz 8
#define Hh 64
#define Ww 64
#define Cc 256
#define Nn 64
#define Ll 4096      /* Hh*Ww */
#define EPSf 1e-5f

typedef __bf16 v8bf __attribute__((ext_vector_type(8)));
typedef float  f32x4 __attribute__((ext_vector_type(4)));

__device__ __forceinline__ float ad_val(float a, float snr) {
    float s = fminf(fmaxf(snr, 0.f), 1.f);
    float scale = 0.6f + 0.4f * s;
    float v = tanhf(a) * scale;
    return fminf(fmaxf(v, -0.99f), 0.99f);
}

// K0: weights -> bf16 MFMA B-fragment order. W_in and Wo' (= Wout*0.25*Cp[k],
// exact pow2 scales) both stored as hi/lo bf16 splits. WB = rowsum(Win)*Bp.
__global__ __launch_bounds__(256) void k0_weights(
    const float* __restrict__ Win, const float* __restrict__ Wout,
    const float* __restrict__ Bp, const float* __restrict__ Cp,
    __bf16* __restrict__ Wh, __bf16* __restrict__ Wl,
    __bf16* __restrict__ Woh, __bf16* __restrict__ Wol,
    float* __restrict__ WB)
{
    const int t = threadIdx.x;
    const int blk = blockIdx.x;
    if (blk < 4) {
        for (int idx = blk * 512 + t; idx < blk * 512 + 512; idx += 256) {
            int tile = idx >> 6, lane = idx & 63;
            int kt = tile >> 2, nt = tile & 3;
            int q = lane >> 4, n = nt * 16 + (lane & 15);
            #pragma unroll
            for (int j = 0; j < 8; ++j) {
                int k = kt * 32 + q * 8 + j;
                float w = Win[n * Cc + k];
                __bf16 h = (__bf16)w;
                Wh[idx * 8 + j] = h;
                Wl[idx * 8 + j] = (__bf16)(w - (float)h);
            }
        }
    } else if (blk < 8) {
        for (int idx = (blk - 4) * 512 + t; idx < (blk - 4) * 512 + 512; idx += 256) {
            int tile = idx >> 6, lane = idx & 63;
            int kt = tile >> 4, ntg = tile & 15;
            int q = lane >> 4, c = ntg * 16 + (lane & 15);
            #pragma unroll
            for (int j = 0; j < 8; ++j) {
                int k = kt * 32 + q * 8 + j;
                float w = Wout[c * Nn + k] * 0.25f * Cp[k];
                __bf16 h = (__bf16)w;
                Woh[idx * 8 + j] = h;
                Wol[idx * 8 + j] = (__bf16)(w - (float)h);
            }
        }
    } else {
        __shared__ float wtmp[256];
        int n = t >> 2, qd = t & 3;
        float s = 0.f;
        const float* wr = Win + (long)n * Cc + qd * 64;
        for (int i = 0; i < 64; ++i) s += wr[i];
        wtmp[t] = s;
        __syncthreads();
        if (t < 64)
            WB[t] = (wtmp[t*4] + wtmp[t*4+1] + wtmp[t*4+2] + wtmp[t*4+3]) * Bp[t];
    }
}

// K1: LN stats + MFMA input projection on raw x (LN folded into epilogue):
//   Bu[p][n] = Bp[n]*s[p]*((x@Win^T)[p][n]) - s[p]*m[p]*WB[n].
// 512 blocks x 256 thr; 2-term bf16 split (xh*Wh + xl*Wh + xh*Wl). (R3-proven.)
__global__ __launch_bounds__(256) void k1_ln_gemm(
    const float* __restrict__ x, const __bf16* __restrict__ Wh,
    const __bf16* __restrict__ Wl, const float* __restrict__ Bp,
    const float* __restrict__ WB, float* __restrict__ Bu,
    float* __restrict__ Mst, float* __restrict__ Sst)
{
    __shared__ float mrow[64], srow[64];
    const int t = threadIdx.x;
    const int lane = t & 63;
    const int wv = __builtin_amdgcn_readfirstlane(t >> 6);
    const long pbase = (long)blockIdx.x * 64;
    const float* xt = x + pbase * Cc;

    for (int rr = 0; rr < 16; ++rr) {
        int r = wv * 16 + rr;
        float4 v = ((const float4*)(xt + (long)r * Cc))[lane];
        float s = v.x + v.y + v.z + v.w;
        float q = v.x*v.x + v.y*v.y + v.z*v.z + v.w*v.w;
        #pragma unroll
        for (int off = 32; off > 0; off >>= 1) {
            s += __shfl_down(s, off);
            q += __shfl_down(q, off);
        }
        if (lane == 0) {
            float m = s * (1.f/256.f);
            float var = fmaxf(q * (1.f/256.f) - m*m, 0.f);
            float r1 = rsqrtf(var + EPSf);
            float v2 = var / (var + EPSf);
            float sc = r1 * rsqrtf(v2 + EPSf);
            mrow[r] = m; srow[r] = sc;
            Mst[pbase + r] = m; Sst[pbase + r] = sc;
        }
    }
    __syncthreads();

    const int q = lane >> 4;
    const int mi = lane & 15;
    const float* xa = xt + (long)(wv * 16 + mi) * Cc + q * 8;

    f32x4 acc[4];
    #pragma unroll
    for (int nt = 0; nt < 4; ++nt) acc[nt] = (f32x4){0.f, 0.f, 0.f, 0.f};

    #pragma unroll
    for (int kt = 0; kt < 8; ++kt) {
        float4 a0 = *(const float4*)(xa + kt * 32);
        float4 a1 = *(const float4*)(xa + kt * 32 + 4);
        float av[8] = {a0.x, a0.y, a0.z, a0.w, a1.x, a1.y, a1.z, a1.w};
        v8bf ah, al;
        #pragma unroll
        for (int j = 0; j < 8; ++j) {
            __bf16 h = (__bf16)av[j];
            ah[j] = h;
            al[j] = (__bf16)(av[j] - (float)h);
        }
        #pragma unroll
        for (int nt = 0; nt < 4; ++nt) {
            v8bf bh = *(const v8bf*)(Wh + ((long)(kt * 4 + nt) * 64 + lane) * 8);
            v8bf bl = *(const v8bf*)(Wl + ((long)(kt * 4 + nt) * 64 + lane) * 8);
            acc[nt] = __builtin_amdgcn_mfma_f32_16x16x32_bf16(ah, bh, acc[nt], 0, 0, 0);
            acc[nt] = __builtin_amdgcn_mfma_f32_16x16x32_bf16(al, bh, acc[nt], 0, 0, 0);
            acc[nt] = __builtin_amdgcn_mfma_f32_16x16x32_bf16(ah, bl, acc[nt], 0, 0, 0);
        }
    }

    #pragma unroll
    for (int nt = 0; nt < 4; ++nt) {
        int n = nt * 16 + mi;
        float bpn = Bp[n];
        float wbn = WB[n];
        #pragma unroll
        for (int reg = 0; reg < 4; ++reg) {
            int p = wv * 16 + q * 4 + reg;
            float m = mrow[p], s = srow[p];
            Bu[(pbase + p) * Nn + n] = s * (acc[nt][reg] * bpn - m * wbn);
        }
    }
}

// K2: chunk carries, register-resident, NO reconstruction: u[64] kept intact,
// fwd + bwd carries are two scalar fmaf chains over the SAME values (exactly
// the R3-proven per-element arithmetic). 256 blocks x 256 thr, wave = chunk.
__global__ __launch_bounds__(256) void k2_carry(
    const float* __restrict__ Bu, const float* __restrict__ A,
    const float* __restrict__ snr, float* __restrict__ E)
{
    const int t = threadIdx.x;
    const int lane = t & 63;
    const int task = blockIdx.x * 4 + (t >> 6);
    const int isCol = task >> 9;
    const int b = (task >> 6) & 7;
    const int j = task & 63;
    const float Ad = ad_val(A[lane], snr[b]);
    const float* src = Bu + ((long)b * Ll + (isCol ? j : j * 64)) * Nn + lane;
    const long stride = isCol ? (long)Ww * Nn : Nn;

    float v[64];
    #pragma unroll
    for (int k = 0; k < 64; ++k) v[k] = src[k * stride];

    float s = 0.f;
    #pragma unroll
    for (int k = 0; k < 64; ++k) s = fmaf(Ad, s, v[k]);
    const int dF = isCol ? 2 : 0;
    E[((dF * 8 + b) * 64 + j) * 64 + lane] = s;

    float sb = 0.f;
    #pragma unroll
    for (int k = 63; k >= 0; --k) sb = fmaf(Ad, sb, v[k]);
    E[(((dF + 1) * 8 + b) * 64 + (63 - j)) * 64 + lane] = sb;
}

// K3: per-sequence carry prefix (exclusive scan, Ad^64 composition).
// 32 blocks (dir*8+b) x 64 thr. (R3-proven arithmetic.)
__global__ __launch_bounds__(64) void k3_prefix(
    const float* __restrict__ E, float* __restrict__ CT,
    const float* __restrict__ A, const float* __restrict__ snr)
{
    const int lane = threadIdx.x;
    const int db = blockIdx.x;
    const int b = db & 7;
    float Ad = ad_val(A[lane], snr[b]);
    float p64 = Ad;
    #pragma unroll
    for (int i = 0; i < 6; ++i) p64 *= p64;        // Ad^64
    const float* e = E + (long)db * 4096 + lane;
    float* ct = CT + (long)db * 4096 + lane;
    float v[64];
    #pragma unroll
    for (int k = 0; k < 64; ++k) v[k] = e[k * 64];
    float c = 0.f;
    #pragma unroll
    for (int k = 0; k < 64; ++k) {
        ct[k * 64] = c;
        c = fmaf(p64, c, v[k]);
    }
}

// K4: apply — u[64] AND hf[64] in registers (no reconstruction), seeded
// fwd + bwd chains over the original u (R3-proven arithmetic), fp32 out.
__global__ __launch_bounds__(256) void k4_apply(
    const float* __restrict__ Bu, const float* __restrict__ CT,
    const float* __restrict__ A, const float* __restrict__ snr,
    float* __restrict__ Srow, float* __restrict__ Scol)
{
    const int t = threadIdx.x;
    const int lane = t & 63;
    const int task = blockIdx.x * 4 + (t >> 6);
    const int isCol = task >> 9;
    const int b = (task >> 6) & 7;
    const int j = task & 63;
    const float Ad = ad_val(A[lane], snr[b]);
    const float* src = Bu + ((long)b * Ll + (isCol ? j : j * 64)) * Nn + lane;
    const long stride = isCol ? (long)Ww * Nn : Nn;
    const int dF = isCol ? 2 : 0;
    const float cf = CT[((dF * 8 + b) * 64 + j) * 64 + lane];
    const float cb = CT[(((dF + 1) * 8 + b) * 64 + (63 - j)) * 64 + lane];

    float v[64];
    #pragma unroll
    for (int k = 0; k < 64; ++k) v[k] = src[k * stride];

    float hf[64];
    float h = cf;
    #pragma unroll
    for (int k = 0; k < 64; ++k) { h = fmaf(Ad, h, v[k]); hf[k] = h; }

    float* out0 = (isCol ? Scol : Srow) +
                  ((long)b * Ll + (isCol ? j : j * 64)) * Nn + lane;
    float sb = cb;
    #pragma unroll
    for (int k = 63; k >= 0; --k) {
        sb = fmaf(Ad, sb, v[k]);
        out0[k * stride] = hf[k] + sb;
    }
}

// K5: MFMA output projection y = (Srow+Scol) @ Wo'^T + D*z (Wo' = 0.25*Cp
// folded). fp32 S staged+added in LDS, then 3-term bf16 split GEMM
// (sh*Wh + sl*Wh + sh*Wl) for fp32-class accuracy. 512 blocks x 256 thr.
__global__ __launch_bounds__(256) void k5_gemm_out(
    const float* __restrict__ Srow, const float* __restrict__ Scol,
    const float* __restrict__ x, const __bf16* __restrict__ Woh,
    const __bf16* __restrict__ Wol, const float* __restrict__ Dp,
    const float* __restrict__ Mst, const float* __restrict__ Sst,
    float* __restrict__ out)
{
    __shared__ float smem[64 * 260];    // S tile (stride 68) -> out tile (260)
    const int t = threadIdx.x;
    const int lane = t & 63;
    const int wv = __builtin_amdgcn_readfirstlane(t >> 6);
    const long pbase = (long)blockIdx.x * 64;
    const int q = lane >> 4;
    const int mi = lane & 15;

    // stage S = Srow + Scol (coalesced float4)
    const float4* Sr = (const float4*)(Srow + pbase * Nn);
    const float4* Sc = (const float4*)(Scol + pbase * Nn);
    #pragma unroll
    for (int i = 0; i < 4; ++i) {
        int fi = i * 256 + t;           // p = fi>>4, n4 = fi&15
        float4 a = Sr[fi], c = Sc[fi];
        *(float4*)&smem[(fi >> 4) * 68 + (fi & 15) * 4] =
            make_float4(a.x + c.x, a.y + c.y, a.z + c.z, a.w + c.w);
    }
    __syncthreads();

    f32x4 acc[4][4];
    #pragma unroll
    for (int mt = 0; mt < 4; ++mt)
        #pragma unroll
        for (int nt = 0; nt < 4; ++nt) acc[mt][nt] = (f32x4){0.f, 0.f, 0.f, 0.f};

    #pragma unroll
    for (int kt = 0; kt < 2; ++kt) {
        v8bf bh[4], bl[4];
        #pragma unroll
        for (int nt = 0; nt < 4; ++nt) {
            long wo = ((long)(kt * 16 + wv * 4 + nt) * 64 + lane) * 8;
            bh[nt] = *(const v8bf*)(Woh + wo);
            bl[nt] = *(const v8bf*)(Wol + wo);
        }
        #pragma unroll
        for (int mt = 0; mt < 4; ++mt) {
            const float* ar = &smem[(mt * 16 + mi) * 68 + q * 8 + kt * 32];
            v8bf sh, sl;
            #pragma unroll
            for (int j = 0; j < 8; ++j) {
                float sv = ar[j];
                __bf16 hh = (__bf16)sv;
                sh[j] = hh;
                sl[j] = (__bf16)(sv - (float)hh);
            }
            #pragma unroll
            for (int nt = 0; nt < 4; ++nt) {
                acc[mt][nt] = __builtin_amdgcn_mfma_f32_16x16x32_bf16(sh, bh[nt], acc[mt][nt], 0, 0, 0);
                acc[mt][nt] = __builtin_amdgcn_mfma_f32_16x16x32_bf16(sl, bh[nt], acc[mt][nt], 0, 0, 0);
                acc[mt][nt] = __builtin_amdgcn_mfma_f32_16x16x32_bf16(sh, bl[nt], acc[mt][nt], 0, 0, 0);
            }
        }
    }
    __syncthreads();                    // S tile dead; reuse smem as out tile
    #pragma unroll
    for (int mt = 0; mt < 4; ++mt)
        #pragma unroll
        for (int nt = 0; nt < 4; ++nt) {
            int c = wv * 64 + nt * 16 + mi;
            #pragma unroll
            for (int reg = 0; reg < 4; ++reg)
                smem[(mt * 16 + q * 4 + reg) * 260 + c] = acc[mt][nt][reg];
        }
    __syncthreads();

    // epilogue: out = acc + D*z, fully coalesced float4 (p wave-uniform per i)
    const float4* xg = (const float4*)(x + pbase * Cc);
    float4* og = (float4*)(out + pbase * Cc);
    const float4 dv = ((const float4*)Dp)[lane];
    #pragma unroll 4
    for (int i = 0; i < 16; ++i) {
        int fi = i * 256 + t;           // p = i*4+wv (wave-uniform), c4 = lane
        int p = i * 4 + wv;
        float4 v = *(const float4*)&smem[p * 260 + lane * 4];
        float m = Mst[pbase + p], s = Sst[pbase + p];
        float4 xv = xg[fi];
        og[fi] = make_float4(v.x + dv.x * ((xv.x - m) * s),
                             v.y + dv.y * ((xv.y - m) * s),
                             v.z + dv.z * ((xv.z - m) * s),
                             v.w + dv.w * ((xv.w - m) * s));
    }
}

extern "C" void kernel_launch(void* const* d_in, const int* in_sizes, int n_in,
                              void* d_out, int out_size, void* d_ws, size_t ws_size,
                              hipStream_t stream)
{
    const float* x    = (const float*)d_in[0];
    const float* snr  = (const float*)d_in[1];
    const float* A    = (const float*)d_in[2];
    const float* Bp   = (const float*)d_in[3];
    const float* Cp   = (const float*)d_in[4];
    const float* Dp   = (const float*)d_in[5];
    const float* Win  = (const float*)d_in[6];
    const float* Wout = (const float*)d_in[7];
    float* out = (float*)d_out;

    char* ws = (char*)d_ws;
    float*  Bu   = (float*)(ws);                                        // 8 MiB
    float*  Srow = (float*)(ws + (size_t)8  * 1024 * 1024);             // 8 MiB
    float*  Scol = (float*)(ws + (size_t)16 * 1024 * 1024);             // 8 MiB
    float*  E    = (float*)(ws + (size_t)24 * 1024 * 1024);             // 512 KiB
    float*  CT   = (float*)(ws + (size_t)24 * 1024 * 1024 + 512*1024);  // 512 KiB
    float*  Mst  = (float*)(ws + (size_t)25 * 1024 * 1024);             // 128 KiB
    float*  Sst  = (float*)(ws + (size_t)25 * 1024 * 1024 + 128*1024);  // 128 KiB
    char*   wbase = ws + (size_t)25 * 1024 * 1024 + 512 * 1024;
    __bf16* Wh   = (__bf16*)(wbase);                                    // 32 KiB
    __bf16* Wl   = (__bf16*)(wbase + 32 * 1024);                        // 32 KiB
    __bf16* Woh  = (__bf16*)(wbase + 64 * 1024);                        // 32 KiB
    __bf16* Wol  = (__bf16*)(wbase + 96 * 1024);                        // 32 KiB
    float*  WB   = (float*)(wbase + 128 * 1024);                        // 256 B

    hipLaunchKernelGGL(k0_weights,  dim3(9),   dim3(256), 0, stream, Win, Wout, Bp, Cp, Wh, Wl, Woh, Wol, WB);
    hipLaunchKernelGGL(k1_ln_gemm,  dim3(512), dim3(256), 0, stream, x, Wh, Wl, Bp, WB, Bu, Mst, Sst);
    hipLaunchKernelGGL(k2_carry,    dim3(256), dim3(256), 0, stream, Bu, A, snr, E);
    hipLaunchKernelGGL(k3_prefix,   dim3(32),  dim3(64),  0, stream, E, CT, A, snr);
    hipLaunchKernelGGL(k4_apply,    dim3(256), dim3(256), 0, stream, Bu, CT, A, snr, Srow, Scol);
    hipLaunchKernelGGL(k5_gemm_out, dim3(512), dim3(256), 0, stream, Srow, Scol, x, Woh, Wol, Dp, Mst, Sst, out);
}